// Round 17
// baseline (1667.435 us; speedup 1.0000x reference)
//
#include <hip/hip_runtime.h>
#include <hip/hip_fp16.h>
#include <math.h>

typedef __bf16 bf16x8 __attribute__((ext_vector_type(8)));
typedef float  f32x4  __attribute__((ext_vector_type(4)));

#define AH  264              // act plane stride (bf16); 132 dw % 32 == 4
#define PXS 68               // pxh stride: 34 dw % 32 == 2 -> 2-way only
#define TOT 589824           // staged weight elems (hi); lo at +TOT

// staged ws layout (bf16, [n][k] transposed, zero-padded K tails)
#define OFF_W0T   0          // [256][64]
#define OFF_WHT   16384      // 4 x [256][256]
#define OFF_W5AT  278528     // [256][256]
#define OFF_W5BT  344064     // [256][64]
#define OFF_W6T   360448     // [256][256]
#define OFF_W7T   425984     // [256][256]
#define OFF_WFT   491520     // [256][256]
#define OFF_WMAT  557056     // [128][256]

__global__ void prep_weights(const float* __restrict__ W0, const float* __restrict__ Wh,
                             const float* __restrict__ W5, const float* __restrict__ W6,
                             const float* __restrict__ W7, const float* __restrict__ Wf,
                             const float* __restrict__ Wm, __bf16* __restrict__ ws) {
  int idx = blockIdx.x * blockDim.x + threadIdx.x;
  if (idx >= TOT) return;
  float v = 0.f;
  if (idx < OFF_WHT)        { int j = idx;            int n=j>>6, k=j&63;   v = (k<60)? W0[k*256+n] : 0.f; }
  else if (idx < OFF_W5AT)  { int j = idx - OFF_WHT;  int i=j>>16, r=j&65535, n=r>>8, k=r&255; v = Wh[i*65536+k*256+n]; }
  else if (idx < OFF_W5BT)  { int j = idx - OFF_W5AT; int n=j>>8, k=j&255;  v = W5[k*256+n]; }
  else if (idx < OFF_W6T)   { int j = idx - OFF_W5BT; int n=j>>6, k=j&63;   v = (k<60)? W5[(256+k)*256+n] : 0.f; }
  else if (idx < OFF_W7T)   { int j = idx - OFF_W6T;  int n=j>>8, k=j&255;  v = W6[k*256+n]; }
  else if (idx < OFF_WFT)   { int j = idx - OFF_W7T;  int n=j>>8, k=j&255;  v = W7[k*256+n]; }
  else if (idx < OFF_WMAT)  { int j = idx - OFF_WFT;  int n=j>>8, k=j&255;  v = Wf[k*256+n]; }
  else                      { int j = idx - OFF_WMAT; int n=j>>8, k=j&255;  v = Wm[k*128+n]; }
  __bf16 hi = (__bf16)v;
  ws[idx] = hi;
  ws[TOT + idx] = (__bf16)(v - (float)hi);
}

// one software-pipeline stage: all fragments for one kc (K=32 chunk)
struct Frag { bf16x8 bh[4], bl[4], ah[4], al[4]; };

__device__ __forceinline__ void load_stage(Frag& f,
    const __bf16* aHi, const __bf16* aLo,
    const __bf16* __restrict__ wHi, const __bf16* __restrict__ wLo,
    int kb, int mBase, int nBase, int lm) {
#pragma unroll
  for (int nt = 0; nt < 4; ++nt) {           // global B first (longest latency)
    const int ro = (nBase + nt*16 + lm)*256 + kb;
    f.bh[nt] = *(const bf16x8*)(wHi + ro);
    f.bl[nt] = *(const bf16x8*)(wLo + ro);
  }
#pragma unroll
  for (int mt = 0; mt < 4; ++mt) {           // LDS A
    const int off = (mBase + mt*16 + lm)*AH + kb;
    f.ah[mt] = *(const bf16x8*)(aHi + off);
    f.al[mt] = *(const bf16x8*)(aLo + off);
  }
}

__device__ __forceinline__ void mfma_stage(const Frag& f, f32x4 (&acc)[4][4]) {
#pragma unroll
  for (int p = 0; p < 3; ++p)                // 3-pass split: hh, hl, lh
#pragma unroll
    for (int mt = 0; mt < 4; ++mt)
#pragma unroll
      for (int nt = 0; nt < 4; ++nt)
        acc[mt][nt] = __builtin_amdgcn_mfma_f32_16x16x32_bf16(
            (p == 2) ? f.al[mt] : f.ah[mt],
            (p == 1) ? f.bl[nt] : f.bh[nt],
            acc[mt][nt], 0, 0, 0);
}

template<int NT>
__device__ __forceinline__ void epi_store(f32x4 (&acc)[4][NT], __bf16* aHi, __bf16* aLo,
    const float* __restrict__ bias, const float* __restrict__ pdW, bool relu,
    int mBase, int nBase, int lm, int kq) {
#pragma unroll
  for (int mt = 0; mt < 4; ++mt)
#pragma unroll
    for (int nt = 0; nt < NT; ++nt) {
      const int col = nBase + nt*16 + lm;
      float bv = bias[col] + (pdW ? pdW[col] : 0.f);
#pragma unroll
      for (int r = 0; r < 4; ++r) {
        const int row = mBase + mt*16 + kq*4 + r;
        float v = acc[mt][nt][r] + bv;
        if (relu) v = fmaxf(v, 0.f);
        __bf16 h = (__bf16)v;
        aHi[row*AH + col] = h;
        aLo[row*AH + col] = (__bf16)(v - (float)h);
      }
    }
}

// px-part chunk (K=64 zero-padded), NT=4, accumulates into acc
__device__ __forceinline__ void px_chunks(f32x4 (&acc)[4][4], const __half* pxh,
    const __bf16* __restrict__ xHi, const __bf16* __restrict__ xLo,
    int mBase, int nBase, int lm, int kq) {
#pragma unroll
  for (int kc = 0; kc < 2; ++kc) {
    const int kb = kc*32 + kq*8;
    bf16x8 bh[4], bl[4], ah[4], al[4];
#pragma unroll
    for (int nt = 0; nt < 4; ++nt) {
      const int ro = (nBase + nt*16 + lm)*64 + kb;
      bh[nt] = *(const bf16x8*)(xHi + ro);
      bl[nt] = *(const bf16x8*)(xLo + ro);
    }
#pragma unroll
    for (int mt = 0; mt < 4; ++mt) {
      const __half* pr = pxh + (mBase + mt*16 + lm)*PXS + kb;
#pragma unroll
      for (int j = 0; j < 8; ++j) {
        float v = __half2float(pr[j]);
        __bf16 h = (__bf16)v;
        ah[mt][j] = h;
        al[mt][j] = (__bf16)(v - (float)h);
      }
    }
#pragma unroll
    for (int p = 0; p < 3; ++p)
#pragma unroll
      for (int mt = 0; mt < 4; ++mt)
#pragma unroll
        for (int nt = 0; nt < 4; ++nt)
          acc[mt][nt] = __builtin_amdgcn_mfma_f32_16x16x32_bf16(
              (p == 2) ? al[mt] : ah[mt],
              (p == 1) ? bl[nt] : bh[nt], acc[mt][nt], 0, 0, 0);
  }
}

// N=256 K=256 layer, software-pipelined (2-stage), in-place, 2 barriers
template<bool USEPX>
__device__ void layer256(__bf16* aHi, __bf16* aLo, const __half* pxh,
    const __bf16* __restrict__ wHi, const __bf16* __restrict__ wLo,
    const __bf16* __restrict__ xHi, const __bf16* __restrict__ xLo,
    const float* __restrict__ bias, bool relu, int tid) {
  const int wave = tid >> 6, lane = tid & 63;
  const int lm = lane & 15, kq = lane >> 4;
  const int mBase = (wave >> 2) * 64;
  const int nBase = (wave & 3) * 64;
  const int kqb = kq * 8;
  f32x4 acc[4][4];
#pragma unroll
  for (int mt = 0; mt < 4; ++mt)
#pragma unroll
    for (int nt = 0; nt < 4; ++nt)
#pragma unroll
      for (int e = 0; e < 4; ++e) acc[mt][nt][e] = 0.f;

  Frag f0, f1;
  load_stage(f0, aHi, aLo, wHi, wLo, 0*32 + kqb, mBase, nBase, lm);
  load_stage(f1, aHi, aLo, wHi, wLo, 1*32 + kqb, mBase, nBase, lm);
#pragma unroll
  for (int kc = 0; kc < 8; kc += 2) {
    mfma_stage(f0, acc);
    if (kc + 2 < 8) load_stage(f0, aHi, aLo, wHi, wLo, (kc+2)*32 + kqb, mBase, nBase, lm);
    mfma_stage(f1, acc);
    if (kc + 3 < 8) load_stage(f1, aHi, aLo, wHi, wLo, (kc+3)*32 + kqb, mBase, nBase, lm);
  }
  if (USEPX) px_chunks(acc, pxh, xHi, xLo, mBase, nBase, lm, kq);
  __syncthreads();                 // all reads of act complete
  epi_store<4>(acc, aHi, aLo, bias, nullptr, relu, mBase, nBase, lm, kq);
  __syncthreads();
}

// layer 0: px-only (act not yet live -> no pre-barrier)
__device__ void layer0(__bf16* aHi, __bf16* aLo, const __half* pxh,
    const __bf16* __restrict__ xHi, const __bf16* __restrict__ xLo,
    const float* __restrict__ bias, int tid) {
  const int wave = tid >> 6, lane = tid & 63;
  const int lm = lane & 15, kq = lane >> 4;
  const int mBase = (wave >> 2) * 64;
  const int nBase = (wave & 3) * 64;
  f32x4 acc[4][4];
#pragma unroll
  for (int mt = 0; mt < 4; ++mt)
#pragma unroll
    for (int nt = 0; nt < 4; ++nt)
#pragma unroll
      for (int e = 0; e < 4; ++e) acc[mt][nt][e] = 0.f;
  px_chunks(acc, pxh, xHi, xLo, mBase, nBase, lm, kq);
  epi_store<4>(acc, aHi, aLo, bias, nullptr, true, mBase, nBase, lm, kq);
  __syncthreads();
}

// Wm layer: N=128, NT=2, pd folded via pdW
__device__ void layerWm(__bf16* aHi, __bf16* aLo,
    const __bf16* __restrict__ wHi, const __bf16* __restrict__ wLo,
    const float* __restrict__ bias, const float* __restrict__ pdW, int tid) {
  const int wave = tid >> 6, lane = tid & 63;
  const int lm = lane & 15, kq = lane >> 4;
  const int mBase = (wave >> 2) * 64;
  const int nBase = (wave & 3) * 32;
  f32x4 acc[4][2];
#pragma unroll
  for (int mt = 0; mt < 4; ++mt)
#pragma unroll
    for (int nt = 0; nt < 2; ++nt)
#pragma unroll
      for (int e = 0; e < 4; ++e) acc[mt][nt][e] = 0.f;
#pragma unroll
  for (int kc = 0; kc < 8; ++kc) {
    const int kb = kc*32 + kq*8;
    bf16x8 bh[2], bl[2], ah[4], al[4];
#pragma unroll
    for (int nt = 0; nt < 2; ++nt) {
      const int ro = (nBase + nt*16 + lm)*256 + kb;
      bh[nt] = *(const bf16x8*)(wHi + ro);
      bl[nt] = *(const bf16x8*)(wLo + ro);
    }
#pragma unroll
    for (int mt = 0; mt < 4; ++mt) {
      const int off = (mBase + mt*16 + lm)*AH + kb;
      ah[mt] = *(const bf16x8*)(aHi + off);
      al[mt] = *(const bf16x8*)(aLo + off);
    }
#pragma unroll
    for (int p = 0; p < 3; ++p)
#pragma unroll
      for (int mt = 0; mt < 4; ++mt)
#pragma unroll
        for (int nt = 0; nt < 2; ++nt)
          acc[mt][nt] = __builtin_amdgcn_mfma_f32_16x16x32_bf16(
              (p == 2) ? al[mt] : ah[mt],
              (p == 1) ? bl[nt] : bh[nt], acc[mt][nt], 0, 0, 0);
  }
  __syncthreads();
  epi_store<2>(acc, aHi, aLo, bias, pdW, true, mBase, nBase, lm, kq);
  __syncthreads();
}

__global__ __launch_bounds__(512, 2) void nerf_main(
    const float* __restrict__ ro, const float* __restrict__ rd, const float* __restrict__ tin,
    const float* __restrict__ b0, const float* __restrict__ bh,
    const float* __restrict__ b5, const float* __restrict__ b6,
    const float* __restrict__ b7,
    const float* __restrict__ Wsig, const float* __restrict__ bs,
    const float* __restrict__ bfb,
    const float* __restrict__ Wm, const float* __restrict__ bm,
    const float* __restrict__ Wr, const float* __restrict__ br,
    const __bf16* __restrict__ wsHi, const __bf16* __restrict__ wsLo,
    float* __restrict__ out) {
  __shared__ __align__(16) __bf16 aHi[128 * AH];          // 67584 B
  __shared__ __align__(16) __bf16 aLo[128 * AH];          // 67584 B
  __shared__ __align__(16) unsigned char pxred[128 * PXS * 2];  // pxh / red union, 17408 B
  __shared__ __align__(16) float  pdBuf[24];
  __shared__ __align__(16) float  pdW[128];
  __shared__ __align__(16) float  tBuf[128];
  __shared__ __align__(16) float  sigBuf[128];
  __shared__ __align__(16) float  rgbBuf[128 * 3];
  // total 155,744 B (<= proven-working 156,160)

  __half* pxh = (__half*)pxred;
  float*  red = (float*)pxred;         // valid after W5 (pxh dead)

  const int ray = blockIdx.x;
  const int tid = threadIdx.x;

  // ---- phase 1: t values + pd ----
  if (tid < 128) tBuf[tid] = tin[ray*128 + tid];
  if (tid >= 128 && tid < 152) {
    int j = tid - 128;
    int i = j / 6, r = j % 6;
    float a = ldexpf(rd[ray*3 + (r % 3)], i);
    pdBuf[j] = (r < 3) ? sinpif(a) : cospif(a);
  }
  __syncthreads();
  // ---- phase 2: positional encodings distributed over all 512 threads ----
  for (int e = tid; e < 128*30; e += 512) {
    int m = e / 30, j = e - m*30;
    int i = j / 3, c = j - i*3;
    float tv = tBuf[m];
    float x = ro[ray*3 + c] + tv * rd[ray*3 + c];
    float a = ldexpf(x, i);                      // sin(2^i*pi*x) = sinpi(2^i*x)
    pxh[m*PXS + i*6 + c]     = __float2half(sinpif(a));
    pxh[m*PXS + i*6 + 3 + c] = __float2half(cospif(a));
  }
  for (int e = tid; e < 128*8; e += 512) {       // zero pad cols 60..67
    int m = e >> 3, j = e & 7;
    pxh[m*PXS + 60 + j] = __float2half(0.f);
  }
  if (tid < 128) {                               // pdW[c] = sum_j pd[j]*Wm[256+j][c]
    float s = 0.f;
#pragma unroll
    for (int j = 0; j < 24; ++j) s += pdBuf[j] * Wm[(256 + j)*128 + tid];
    pdW[tid] = s;
  }
  __syncthreads();

  // ---- trunk ----
  layer0(aHi, aLo, pxh, wsHi + OFF_W0T, wsLo + OFF_W0T, b0, tid);
  for (int i = 0; i < 4; ++i)
    layer256<false>(aHi, aLo, pxh, wsHi + OFF_WHT + i*65536, wsLo + OFF_WHT + i*65536,
                    nullptr, nullptr, bh + i*256, true, tid);
  layer256<true >(aHi, aLo, pxh, wsHi + OFF_W5AT, wsLo + OFF_W5AT,
                  wsHi + OFF_W5BT, wsLo + OFF_W5BT, b5, true, tid);
  layer256<false>(aHi, aLo, pxh, wsHi + OFF_W6T, wsLo + OFF_W6T,
                  nullptr, nullptr, b6, true, tid);
  layer256<false>(aHi, aLo, pxh, wsHi + OFF_W7T, wsLo + OFF_W7T,
                  nullptr, nullptr, b7, true, tid);

  // sigma = relu(h @ Ws + bs): 4 threads/sample over K=256  (pxh dead -> red)
  {
    const int m = tid >> 2, q = tid & 3;
    float s = 0.f;
    for (int k = q*64; k < q*64 + 64; ++k)
      s += ((float)aHi[m*AH + k] + (float)aLo[m*AH + k]) * Wsig[k];
    red[tid] = s;
    __syncthreads();
    if (tid < 128) {
      float sm = bs[0];
#pragma unroll
      for (int j = 0; j < 4; ++j) sm += red[4*tid + j];
      sigBuf[tid] = fmaxf(sm, 0.f);
    }
    __syncthreads();
  }

  // feat = h @ Wf + bf (no relu)
  layer256<false>(aHi, aLo, pxh, wsHi + OFF_WFT, wsLo + OFF_WFT,
                  nullptr, nullptr, bfb, false, tid);
  // h2 = relu([feat, pd] @ Wm + bm), N=128
  layerWm(aHi, aLo, wsHi + OFF_WMAT, wsLo + OFF_WMAT, bm, pdW, tid);

  // rgb = sigmoid(h2 @ Wr + br): 4 threads/sample over K=128
  {
    const int m = tid >> 2, q = tid & 3;
    float r0s = 0.f, r1s = 0.f, r2s = 0.f;
    for (int k = q*32; k < q*32 + 32; ++k) {
      float hv = (float)aHi[m*AH + k] + (float)aLo[m*AH + k];
      r0s += hv * Wr[k*3 + 0];
      r1s += hv * Wr[k*3 + 1];
      r2s += hv * Wr[k*3 + 2];
    }
    red[tid] = r0s; red[512 + tid] = r1s; red[1024 + tid] = r2s;
    __syncthreads();
    if (tid < 128) {
#pragma unroll
      for (int c = 0; c < 3; ++c) {
        float sm = br[c];
#pragma unroll
        for (int j = 0; j < 4; ++j) sm += red[c*512 + 4*tid + j];
        rgbBuf[tid*3 + c] = 1.f / (1.f + expf(-sm));
      }
    }
    __syncthreads();
  }

  // volume rendering: serial exclusive-transmittance scan
  if (tid == 0) {
    float T = 1.f, c0 = 0.f, c1 = 0.f, c2 = 0.f, wsum = 0.f;
    for (int m = 0; m < 128; ++m) {
      float delta = (m < 127) ? (tBuf[m + 1] - tBuf[m]) : 1e8f;
      float e = expf(-sigBuf[m] * delta);
      float w = T * (1.f - e);
      c0 += w * rgbBuf[m*3 + 0];
      c1 += w * rgbBuf[m*3 + 1];
      c2 += w * rgbBuf[m*3 + 2];
      wsum += w;
      T *= e;
    }
    float bg = 1.f - wsum;               // C_BG = (1,1,1)
    out[ray*3 + 0] = c0 + bg;
    out[ray*3 + 1] = c1 + bg;
    out[ray*3 + 2] = c2 + bg;
  }
}

extern "C" void kernel_launch(void* const* d_in, const int* in_sizes, int n_in,
                              void* d_out, int out_size, void* d_ws, size_t ws_size,
                              hipStream_t stream) {
  const float* ro  = (const float*)d_in[0];
  const float* rd  = (const float*)d_in[1];
  const float* t   = (const float*)d_in[2];
  const float* W0  = (const float*)d_in[3];
  const float* b0  = (const float*)d_in[4];
  const float* Wh  = (const float*)d_in[5];
  const float* bh  = (const float*)d_in[6];
  const float* W5  = (const float*)d_in[7];
  const float* b5  = (const float*)d_in[8];
  const float* W6  = (const float*)d_in[9];
  const float* b6  = (const float*)d_in[10];
  const float* W7  = (const float*)d_in[11];
  const float* b7  = (const float*)d_in[12];
  const float* Wsg = (const float*)d_in[13];
  const float* bs  = (const float*)d_in[14];
  const float* Wf  = (const float*)d_in[15];
  const float* bfb = (const float*)d_in[16];
  const float* Wm  = (const float*)d_in[17];
  const float* bm  = (const float*)d_in[18];
  const float* Wr  = (const float*)d_in[19];
  const float* br  = (const float*)d_in[20];
  float* out = (float*)d_out;

  __bf16* wsHi = (__bf16*)d_ws;        // 2*TOT bf16 = 2.36 MB (proven present since r9)
  __bf16* wsLo = wsHi + TOT;

  prep_weights<<<(TOT + 255)/256, 256, 0, stream>>>(W0, Wh, W5, W6, W7, Wf, Wm, wsHi);
  nerf_main<<<2048, 512, 0, stream>>>(ro, rd, t, b0, bh, b5, b6, b7,
                                      Wsg, bs, bfb, Wm, bm, Wr, br,
                                      wsHi, wsLo, out);
}

// Round 18
// 1522.611 us; speedup vs baseline: 1.0951x; 1.0951x over previous
//
#include <hip/hip_runtime.h>
#include <hip/hip_fp16.h>
#include <math.h>

typedef __bf16 bf16x8 __attribute__((ext_vector_type(8)));
typedef float  f32x4  __attribute__((ext_vector_type(4)));

#define AH  264              // act plane stride (bf16); 132 dw % 32 == 4 -> 2-way only
#define PXS 68               // pxh stride: 34 dw % 32 == 2 -> 2-way only
#define TOT 589824           // staged weight elems (hi); lo at +TOT

// staged ws layout (bf16, [n][k] transposed, zero-padded K tails)
#define OFF_W0T   0          // [256][64]
#define OFF_WHT   16384      // 4 x [256][256]
#define OFF_W5AT  278528     // [256][256]
#define OFF_W5BT  344064     // [256][64]
#define OFF_W6T   360448     // [256][256]
#define OFF_W7T   425984     // [256][256]
#define OFF_WFT   491520     // [256][256]
#define OFF_WMAT  557056     // [128][256]

__global__ void prep_weights(const float* __restrict__ W0, const float* __restrict__ Wh,
                             const float* __restrict__ W5, const float* __restrict__ W6,
                             const float* __restrict__ W7, const float* __restrict__ Wf,
                             const float* __restrict__ Wm, __bf16* __restrict__ ws) {
  int idx = blockIdx.x * blockDim.x + threadIdx.x;
  if (idx >= TOT) return;
  float v = 0.f;
  if (idx < OFF_WHT)        { int j = idx;            int n=j>>6, k=j&63;   v = (k<60)? W0[k*256+n] : 0.f; }
  else if (idx < OFF_W5AT)  { int j = idx - OFF_WHT;  int i=j>>16, r=j&65535, n=r>>8, k=r&255; v = Wh[i*65536+k*256+n]; }
  else if (idx < OFF_W5BT)  { int j = idx - OFF_W5AT; int n=j>>8, k=j&255;  v = W5[k*256+n]; }
  else if (idx < OFF_W6T)   { int j = idx - OFF_W5BT; int n=j>>6, k=j&63;   v = (k<60)? W5[(256+k)*256+n] : 0.f; }
  else if (idx < OFF_W7T)   { int j = idx - OFF_W6T;  int n=j>>8, k=j&255;  v = W6[k*256+n]; }
  else if (idx < OFF_WFT)   { int j = idx - OFF_W7T;  int n=j>>8, k=j&255;  v = W7[k*256+n]; }
  else if (idx < OFF_WMAT)  { int j = idx - OFF_WFT;  int n=j>>8, k=j&255;  v = Wf[k*256+n]; }
  else                      { int j = idx - OFF_WMAT; int n=j>>8, k=j&255;  v = Wm[k*128+n]; }
  __bf16 hi = (__bf16)v;
  ws[idx] = hi;
  ws[TOT + idx] = (__bf16)(v - (float)hi);
}

// one pipeline stage for M=64/NT=2: 48 regs (ah/al 32 + bh/bl 16)
struct Frag { bf16x8 ah[4], al[4], bh[2], bl[2]; };

__device__ __forceinline__ void load_stage(Frag& f,
    const __bf16* aHi, const __bf16* aLo,
    const __bf16* __restrict__ wHi, const __bf16* __restrict__ wLo,
    int kb, int nBase, int lm) {
#pragma unroll
  for (int nt = 0; nt < 2; ++nt) {           // global B first (longest latency)
    const int ro = (nBase + nt*16 + lm)*256 + kb;
    f.bh[nt] = *(const bf16x8*)(wHi + ro);
    f.bl[nt] = *(const bf16x8*)(wLo + ro);
  }
#pragma unroll
  for (int mt = 0; mt < 4; ++mt) {           // LDS A (rows 0..63)
    const int off = (mt*16 + lm)*AH + kb;
    f.ah[mt] = *(const bf16x8*)(aHi + off);
    f.al[mt] = *(const bf16x8*)(aLo + off);
  }
}

__device__ __forceinline__ void mfma_stage(const Frag& f, f32x4 (&acc)[4][2]) {
#pragma unroll
  for (int p = 0; p < 3; ++p)                // 3-pass split: hh, hl, lh
#pragma unroll
    for (int mt = 0; mt < 4; ++mt)
#pragma unroll
      for (int nt = 0; nt < 2; ++nt)
        acc[mt][nt] = __builtin_amdgcn_mfma_f32_16x16x32_bf16(
            (p == 2) ? f.al[mt] : f.ah[mt],
            (p == 1) ? f.bl[nt] : f.bh[nt],
            acc[mt][nt], 0, 0, 0);
}

template<int NT>
__device__ __forceinline__ void epi_store(f32x4 (&acc)[4][NT], __bf16* aHi, __bf16* aLo,
    const float* __restrict__ bias, const float* __restrict__ pdW, bool relu,
    int nBase, int lm, int kq) {
#pragma unroll
  for (int mt = 0; mt < 4; ++mt)
#pragma unroll
    for (int nt = 0; nt < NT; ++nt) {
      const int col = nBase + nt*16 + lm;
      float bv = bias[col] + (pdW ? pdW[col] : 0.f);
#pragma unroll
      for (int r = 0; r < 4; ++r) {
        const int row = mt*16 + kq*4 + r;
        float v = acc[mt][nt][r] + bv;
        if (relu) v = fmaxf(v, 0.f);
        __bf16 h = (__bf16)v;
        aHi[row*AH + col] = h;
        aLo[row*AH + col] = (__bf16)(v - (float)h);
      }
    }
}

// px-part (K=64 zero-padded), NT=2, accumulates into acc
__device__ __forceinline__ void px_chunks(f32x4 (&acc)[4][2], const __half* pxh,
    const __bf16* __restrict__ xHi, const __bf16* __restrict__ xLo,
    int nBase, int lm, int kq) {
#pragma unroll
  for (int kc = 0; kc < 2; ++kc) {
    const int kb = kc*32 + kq*8;
    bf16x8 bh[2], bl[2], ah[4], al[4];
#pragma unroll
    for (int nt = 0; nt < 2; ++nt) {
      const int ro = (nBase + nt*16 + lm)*64 + kb;
      bh[nt] = *(const bf16x8*)(xHi + ro);
      bl[nt] = *(const bf16x8*)(xLo + ro);
    }
#pragma unroll
    for (int mt = 0; mt < 4; ++mt) {
      const __half* pr = pxh + (mt*16 + lm)*PXS + kb;
#pragma unroll
      for (int j = 0; j < 8; ++j) {
        float v = __half2float(pr[j]);
        __bf16 h = (__bf16)v;
        ah[mt][j] = h;
        al[mt][j] = (__bf16)(v - (float)h);
      }
    }
#pragma unroll
    for (int p = 0; p < 3; ++p)
#pragma unroll
      for (int mt = 0; mt < 4; ++mt)
#pragma unroll
        for (int nt = 0; nt < 2; ++nt)
          acc[mt][nt] = __builtin_amdgcn_mfma_f32_16x16x32_bf16(
              (p == 2) ? al[mt] : ah[mt],
              (p == 1) ? bl[nt] : bh[nt], acc[mt][nt], 0, 0, 0);
  }
}

// N=256 K=256 layer, 2-deep software pipeline, in-place, 2 barriers.
// 8 waves, wave covers rows 0..63 (4 m-tiles) x cols [wave*32, wave*32+32).
template<bool USEPX>
__device__ void layer256(__bf16* aHi, __bf16* aLo, const __half* pxh,
    const __bf16* __restrict__ wHi, const __bf16* __restrict__ wLo,
    const __bf16* __restrict__ xHi, const __bf16* __restrict__ xLo,
    const float* __restrict__ bias, bool relu, int tid) {
  const int wave = tid >> 6, lane = tid & 63;
  const int lm = lane & 15, kq = lane >> 4;
  const int nBase = wave * 32;
  const int kqb = kq * 8;
  f32x4 acc[4][2];
#pragma unroll
  for (int mt = 0; mt < 4; ++mt)
#pragma unroll
    for (int nt = 0; nt < 2; ++nt)
#pragma unroll
      for (int e = 0; e < 4; ++e) acc[mt][nt][e] = 0.f;

  Frag f0, f1;
  load_stage(f0, aHi, aLo, wHi, wLo, 0*32 + kqb, nBase, lm);
  load_stage(f1, aHi, aLo, wHi, wLo, 1*32 + kqb, nBase, lm);
#pragma unroll
  for (int kc = 0; kc < 8; kc += 2) {
    mfma_stage(f0, acc);
    if (kc + 2 < 8) load_stage(f0, aHi, aLo, wHi, wLo, (kc+2)*32 + kqb, nBase, lm);
    mfma_stage(f1, acc);
    if (kc + 3 < 8) load_stage(f1, aHi, aLo, wHi, wLo, (kc+3)*32 + kqb, nBase, lm);
  }
  if (USEPX) px_chunks(acc, pxh, xHi, xLo, nBase, lm, kq);
  __syncthreads();                 // all reads of act complete
  epi_store<2>(acc, aHi, aLo, bias, nullptr, relu, nBase, lm, kq);
  __syncthreads();
}

// layer 0: px-only (act not yet live -> no pre-barrier)
__device__ void layer0(__bf16* aHi, __bf16* aLo, const __half* pxh,
    const __bf16* __restrict__ xHi, const __bf16* __restrict__ xLo,
    const float* __restrict__ bias, int tid) {
  const int wave = tid >> 6, lane = tid & 63;
  const int lm = lane & 15, kq = lane >> 4;
  const int nBase = wave * 32;
  f32x4 acc[4][2];
#pragma unroll
  for (int mt = 0; mt < 4; ++mt)
#pragma unroll
    for (int nt = 0; nt < 2; ++nt)
#pragma unroll
      for (int e = 0; e < 4; ++e) acc[mt][nt][e] = 0.f;
  px_chunks(acc, pxh, xHi, xLo, nBase, lm, kq);
  epi_store<2>(acc, aHi, aLo, bias, nullptr, true, nBase, lm, kq);
  __syncthreads();
}

// Wm layer: N=128, NT=1 (8 waves x 16 cols), pd folded via pdW
__device__ void layerWm(__bf16* aHi, __bf16* aLo,
    const __bf16* __restrict__ wHi, const __bf16* __restrict__ wLo,
    const float* __restrict__ bias, const float* __restrict__ pdW, int tid) {
  const int wave = tid >> 6, lane = tid & 63;
  const int lm = lane & 15, kq = lane >> 4;
  const int nBase = wave * 16;
  f32x4 acc[4][1];
#pragma unroll
  for (int mt = 0; mt < 4; ++mt)
#pragma unroll
    for (int e = 0; e < 4; ++e) acc[mt][0][e] = 0.f;
#pragma unroll
  for (int kc = 0; kc < 8; ++kc) {
    const int kb = kc*32 + kq*8;
    bf16x8 bh, bl, ah[4], al[4];
    {
      const int ro = (nBase + lm)*256 + kb;
      bh = *(const bf16x8*)(wHi + ro);
      bl = *(const bf16x8*)(wLo + ro);
    }
#pragma unroll
    for (int mt = 0; mt < 4; ++mt) {
      const int off = (mt*16 + lm)*AH + kb;
      ah[mt] = *(const bf16x8*)(aHi + off);
      al[mt] = *(const bf16x8*)(aLo + off);
    }
#pragma unroll
    for (int p = 0; p < 3; ++p)
#pragma unroll
      for (int mt = 0; mt < 4; ++mt)
        acc[mt][0] = __builtin_amdgcn_mfma_f32_16x16x32_bf16(
            (p == 2) ? al[mt] : ah[mt],
            (p == 1) ? bl : bh, acc[mt][0], 0, 0, 0);
  }
  __syncthreads();
  epi_store<1>(acc, aHi, aLo, bias, pdW, true, nBase, lm, kq);
  __syncthreads();
}

// blockIdx = ray*2 + half; covers samples [half*64, half*64+64)
__global__ __launch_bounds__(512, 2) void nerf_main(
    const float* __restrict__ ro, const float* __restrict__ rd, const float* __restrict__ tin,
    const float* __restrict__ b0, const float* __restrict__ bh,
    const float* __restrict__ b5, const float* __restrict__ b6,
    const float* __restrict__ b7,
    const float* __restrict__ Wsig, const float* __restrict__ bs,
    const float* __restrict__ bfb,
    const float* __restrict__ Wm, const float* __restrict__ bm,
    const float* __restrict__ Wr, const float* __restrict__ br,
    const __bf16* __restrict__ wsHi, const __bf16* __restrict__ wsLo,
    float* __restrict__ part) {
  __shared__ __align__(16) __bf16 aHi[64 * AH];           // 33792 B
  __shared__ __align__(16) __bf16 aLo[64 * AH];           // 33792 B
  __shared__ __align__(16) unsigned char pxred[64 * PXS * 2];  // pxh / red union, 8704 B
  __shared__ __align__(16) float  pdBuf[24];
  __shared__ __align__(16) float  pdW[128];
  __shared__ __align__(16) float  tBuf[68];
  __shared__ __align__(16) float  sigBuf[64];
  __shared__ __align__(16) float  rgbBuf[64 * 3];

  __half* pxh = (__half*)pxred;
  float*  red = (float*)pxred;         // valid after W5 (pxh dead)

  const int blk = blockIdx.x;
  const int ray = blk >> 1;
  const int S   = (blk & 1) * 64;
  const int tid = threadIdx.x;

  // ---- phase 1: t values + pd ----
  if (tid < 64) tBuf[tid] = tin[ray*128 + S + tid];
  if (tid >= 64 && tid < 88) {
    int j = tid - 64;
    int i = j / 6, r = j % 6;
    float a = ldexpf(rd[ray*3 + (r % 3)], i);
    pdBuf[j] = (r < 3) ? sinpif(a) : cospif(a);
  }
  if (tid == 88) tBuf[64] = (S + 64 < 128) ? tin[ray*128 + S + 64] : 0.f;
  __syncthreads();
  // ---- phase 2: PE distributed over all 512 threads ----
  for (int e = tid; e < 64*30; e += 512) {
    int m = e / 30, j = e - m*30;
    int i = j / 3, c = j - i*3;
    float tv = tBuf[m];
    float x = ro[ray*3 + c] + tv * rd[ray*3 + c];
    float a = ldexpf(x, i);                      // sin(2^i*pi*x) = sinpi(2^i*x)
    pxh[m*PXS + i*6 + c]     = __float2half(sinpif(a));
    pxh[m*PXS + i*6 + 3 + c] = __float2half(cospif(a));
  }
  for (int e = tid; e < 64*8; e += 512) {        // zero pad cols 60..67
    int m = e >> 3, j = e & 7;
    pxh[m*PXS + 60 + j] = __float2half(0.f);
  }
  if (tid < 128) {                               // pdW[c] = sum_j pd[j]*Wm[256+j][c]
    float s = 0.f;
#pragma unroll
    for (int j = 0; j < 24; ++j) s += pdBuf[j] * Wm[(256 + j)*128 + tid];
    pdW[tid] = s;
  }
  __syncthreads();

  // ---- trunk ----
  layer0(aHi, aLo, pxh, wsHi + OFF_W0T, wsLo + OFF_W0T, b0, tid);
  for (int i = 0; i < 4; ++i)
    layer256<false>(aHi, aLo, pxh, wsHi + OFF_WHT + i*65536, wsLo + OFF_WHT + i*65536,
                    nullptr, nullptr, bh + i*256, true, tid);
  layer256<true >(aHi, aLo, pxh, wsHi + OFF_W5AT, wsLo + OFF_W5AT,
                  wsHi + OFF_W5BT, wsLo + OFF_W5BT, b5, true, tid);
  layer256<false>(aHi, aLo, pxh, wsHi + OFF_W6T, wsLo + OFF_W6T,
                  nullptr, nullptr, b6, true, tid);
  layer256<false>(aHi, aLo, pxh, wsHi + OFF_W7T, wsLo + OFF_W7T,
                  nullptr, nullptr, b7, true, tid);

  // sigma = relu(h @ Ws + bs): 8 threads/sample over K=256 (pxh dead -> red)
  {
    const int m = tid >> 3, q = tid & 7;
    float s = 0.f;
    for (int k = q*32; k < q*32 + 32; ++k)
      s += ((float)aHi[m*AH + k] + (float)aLo[m*AH + k]) * Wsig[k];
    red[tid] = s;
    __syncthreads();
    if (tid < 64) {
      float sm = bs[0];
#pragma unroll
      for (int j = 0; j < 8; ++j) sm += red[8*tid + j];
      sigBuf[tid] = fmaxf(sm, 0.f);
    }
    __syncthreads();
  }

  // feat = h @ Wf + bf (no relu)
  layer256<false>(aHi, aLo, pxh, wsHi + OFF_WFT, wsLo + OFF_WFT,
                  nullptr, nullptr, bfb, false, tid);
  // h2 = relu([feat, pd] @ Wm + bm), N=128
  layerWm(aHi, aLo, wsHi + OFF_WMAT, wsLo + OFF_WMAT, bm, pdW, tid);

  // rgb = sigmoid(h2 @ Wr + br): 8 threads/sample over K=128
  {
    const int m = tid >> 3, q = tid & 7;
    float r0s = 0.f, r1s = 0.f, r2s = 0.f;
    for (int k = q*16; k < q*16 + 16; ++k) {
      float hv = (float)aHi[m*AH + k] + (float)aLo[m*AH + k];
      r0s += hv * Wr[k*3 + 0];
      r1s += hv * Wr[k*3 + 1];
      r2s += hv * Wr[k*3 + 2];
    }
    red[tid] = r0s; red[512 + tid] = r1s; red[1024 + tid] = r2s;
    __syncthreads();
    if (tid < 64) {
#pragma unroll
      for (int c = 0; c < 3; ++c) {
        float sm = br[c];
#pragma unroll
        for (int j = 0; j < 8; ++j) sm += red[c*512 + 8*tid + j];
        rgbBuf[tid*3 + c] = 1.f / (1.f + expf(-sm));
      }
    }
    __syncthreads();
  }

  // segment transmittance scan -> partials
  if (tid == 0) {
    float T = 1.f, c0 = 0.f, c1 = 0.f, c2 = 0.f, wsum = 0.f;
    for (int m = 0; m < 64; ++m) {
      float delta = (S + m < 127) ? (tBuf[m + 1] - tBuf[m]) : 1e8f;
      float e = expf(-sigBuf[m] * delta);
      float w = T * (1.f - e);
      c0 += w * rgbBuf[m*3 + 0];
      c1 += w * rgbBuf[m*3 + 1];
      c2 += w * rgbBuf[m*3 + 2];
      wsum += w;
      T *= e;
    }
    float* p = part + blk*5;
    p[0] = c0; p[1] = c1; p[2] = c2; p[3] = wsum; p[4] = T;
  }
}

__global__ void combine(const float* __restrict__ part, float* __restrict__ out) {
  int r = blockIdx.x * blockDim.x + threadIdx.x;
  if (r >= 2048) return;
  const float* p0 = part + (2*r)*5;
  const float* p1 = p0 + 5;
  float T0 = p0[4];
  float wsum = p0[3] + T0 * p1[3];
  float bg = 1.f - wsum;               // C_BG = (1,1,1)
#pragma unroll
  for (int c = 0; c < 3; ++c)
    out[r*3 + c] = p0[c] + T0 * p1[c] + bg;
}

extern "C" void kernel_launch(void* const* d_in, const int* in_sizes, int n_in,
                              void* d_out, int out_size, void* d_ws, size_t ws_size,
                              hipStream_t stream) {
  const float* ro  = (const float*)d_in[0];
  const float* rd  = (const float*)d_in[1];
  const float* t   = (const float*)d_in[2];
  const float* W0  = (const float*)d_in[3];
  const float* b0  = (const float*)d_in[4];
  const float* Wh  = (const float*)d_in[5];
  const float* bh  = (const float*)d_in[6];
  const float* W5  = (const float*)d_in[7];
  const float* b5  = (const float*)d_in[8];
  const float* W6  = (const float*)d_in[9];
  const float* b6  = (const float*)d_in[10];
  const float* W7  = (const float*)d_in[11];
  const float* b7  = (const float*)d_in[12];
  const float* Wsg = (const float*)d_in[13];
  const float* bs  = (const float*)d_in[14];
  const float* Wf  = (const float*)d_in[15];
  const float* bfb = (const float*)d_in[16];
  const float* Wm  = (const float*)d_in[17];
  const float* bm  = (const float*)d_in[18];
  const float* Wr  = (const float*)d_in[19];
  const float* br  = (const float*)d_in[20];
  float* out = (float*)d_out;

  __bf16* wsHi = (__bf16*)d_ws;                     // 2*TOT bf16 = 2.36 MB
  __bf16* wsLo = wsHi + TOT;
  float*  part = (float*)((char*)d_ws + (size_t)2 * TOT * 2);   // 4096*5 floats = 80 KB
  // ws_size sufficiency proven: r13-r16 all ran this exact split layout and passed.

  prep_weights<<<(TOT + 255)/256, 256, 0, stream>>>(W0, Wh, W5, W6, W7, Wf, Wm, wsHi);
  nerf_main<<<4096, 512, 0, stream>>>(ro, rd, t, b0, bh, b5, b6, b7,
                                      Wsg, bs, bfb, Wm, bm, Wr, br,
                                      wsHi, wsLo, part);
  combine<<<8, 256, 0, stream>>>(part, out);
}